// Round 1
// baseline (179.580 us; speedup 1.0000x reference)
//
#include <hip/hip_runtime.h>

// ---------------------------------------------------------------------------
// ConvFeatureExtractor: profile = rownorm( freq @ softmax(matches/T, axis=1)^T )
//   matches[f,i] = Thi[f, i>>6] + Tlo[f, i&63]  (separable!), F=8192, M=4096,
//   B=1024, K=6.  =>  probs[f,i] = e1[f,i>>6] * e2[f,i&63],  Z = (sum e1)(sum e2).
// R7: break the m97-structure ceiling (35% MfmaUtil @ 80us). New gemm:
//   tile 128x256, 512 thr (8 waves, wave tile 64x64 = 4x4 frags), grid 32x8 =
//   256 blocks = 1/CU. A-only LDS, 3-deep pipeline, raw s_barrier + counted
//   s_waitcnt vmcnt(2) (loads stay in flight across barriers), e1 prefetched
//   one kt ahead, per-j phase split with s_setprio around the MFMA cluster.
// ---------------------------------------------------------------------------

typedef __bf16  bf16x8 __attribute__((ext_vector_type(8)));
typedef float   f32x4  __attribute__((ext_vector_type(4)));

#define GLD16(gp, lp)                                                          \
  __builtin_amdgcn_global_load_lds(                                            \
      (const __attribute__((address_space(1))) void*)(gp),                     \
      (__attribute__((address_space(3))) void*)(lp), 16, 0, 0)

__device__ __forceinline__ short f2bf(float x) {
  unsigned u = __float_as_uint(x);
  unsigned r = (u + 0x7fffu + ((u >> 16) & 1u)) >> 16;   // RNE
  return (short)r;
}

__device__ __forceinline__ float wave_max(float v) {
  #pragma unroll
  for (int off = 32; off; off >>= 1) v = fmaxf(v, __shfl_xor(v, off, 64));
  return v;
}
__device__ __forceinline__ float wave_sum(float v) {
  #pragma unroll
  for (int off = 32; off; off >>= 1) v += __shfl_xor(v, off, 64);
  return v;
}

// ---------------- k1: freq f32 -> bf16 ----------------
__global__ __launch_bounds__(256) void cast_kernel(const float* __restrict__ in,
                                                   short* __restrict__ out) {
  int idx = blockIdx.x * 256 + threadIdx.x;      // 4 floats each
  float4 v = ((const float4*)in)[idx];
  short4 o;
  o.x = f2bf(v.x); o.y = f2bf(v.y); o.z = f2bf(v.z); o.w = f2bf(v.w);
  ((short4*)out)[idx] = o;
}

// ---------------- k2: softmax factor tables ----------------
// One wave per filter (4 filters/block). lane l:
//   Thi_l = P[d0*6+0]+P[d1*6+1]+P[d2*6+2], Tlo_l = P[d0*6+3]+P[d1*6+4]+P[d2*6+5]
// e1 = exp((Thi-mxhi)/T), e2 = exp((Tlo-mxlo)/T), Z = (sum e1)(sum e2).
// E1t[l][f] (transposed, f32, 1/Z folded in) for coalesced GEMM reads;
// E2[f][l] (f32).
__global__ __launch_bounds__(256) void tables_kernel(const float* __restrict__ kp,
                                                     const float* __restrict__ temp,
                                                     float* __restrict__ E1t,
                                                     float* __restrict__ E2) {
  const int t = threadIdx.x;
  const int lane = t & 63, wave = t >> 6;
  const int f = blockIdx.x * 4 + wave;
  const float* P = kp + f * 24;
  const int d0 = (lane >> 4) & 3, d1 = (lane >> 2) & 3, d2 = lane & 3;
  const float thi = P[d0 * 6 + 0] + P[d1 * 6 + 1] + P[d2 * 6 + 2];
  const float tlo = P[d0 * 6 + 3] + P[d1 * 6 + 4] + P[d2 * 6 + 5];
  const float mxhi = wave_max(thi), mxlo = wave_max(tlo);
  const float invT = 1.0f / temp[0];
  const float e1 = __expf((thi - mxhi) * invT);
  const float e2 = __expf((tlo - mxlo) * invT);
  const float s1 = wave_sum(e1), s2 = wave_sum(e2);
  const float invZ = 1.0f / (s1 * s2);
  E1t[lane * 8192 + f] = e1 * invZ;
  E2[(size_t)f * 64 + lane] = e2;
}

// ---------------- k3: GEMM pooled = A(1024x4096) * B^T, B[f,i]=e1[f,i>>6]e2[f,i&63]
// Tiles: TM=128, TN=256, BK=64; grid 32x8 = 256 blocks (1/CU, 8 waves).
// Wave grid 2(m) x 4(n): per-wave 64x64 = 4x4 frags of 16x16x32, acc = 64 VGPR.
// Only A staged in LDS (XOR-swizzled source, linear dest), 3-deep pipeline:
//   iter kt: vmcnt(2); s_barrier; copy e1; issue e1(kt+1); issue stage(kt+2);
//            4 phases { build b[j], setprio(1), 8 MFMA, setprio(0) }.
// Counted vmcnt: stage(kt+1)'s 2 loads remain in flight across the barrier.
__global__ __launch_bounds__(512, 2) void gemm_kernel(const short* __restrict__ A,
                                                      const float* __restrict__ E1t,
                                                      const float* __restrict__ E2,
                                                      float* __restrict__ C) {
  __shared__ short As[3 * 128 * 64];             // 3 x 16 KiB pipeline buffers

  const int t = threadIdx.x;
  const int lane = t & 63, wave = t >> 6;
  const int quad = lane >> 4, l16 = lane & 15;
  const int m0 = blockIdx.y * 128;               // batch tile
  const int n0 = blockIdx.x * 256;               // filter tile
  const int wm = (wave >> 2) * 64;               // wave m-offset (0/64)
  const int wn = (wave & 3) * 64;                // wave n-offset (0..192)

  f32x4 acc[4][4];
  #pragma unroll
  for (int i = 0; i < 4; i++)
    #pragma unroll
    for (int j = 0; j < 4; j++) acc[i][j] = (f32x4){0.f, 0.f, 0.f, 0.f};

  // preload e2 fragments (f32): lane (l16,quad) of frag (j,ks) covers
  // k-in-slice = (ks*4+quad)*8 + 0..7 for filter row nrow[j]
  int nrow[4];
  #pragma unroll
  for (int j = 0; j < 4; j++) nrow[j] = n0 + wn + j * 16 + l16;
  float4 e2a[4][2], e2b[4][2];
  #pragma unroll
  for (int j = 0; j < 4; j++)
    #pragma unroll
    for (int ks = 0; ks < 2; ks++) {
      const float* p = E2 + (size_t)nrow[j] * 64 + (ks * 4 + quad) * 8;
      e2a[j][ks] = *(const float4*)p;
      e2b[j][ks] = *(const float4*)(p + 4);
    }

  const int lane_row = lane >> 3;                      // 0..7 within 8-row unit
  const int src_col = ((lane & 7) ^ lane_row) * 8;     // swizzled global col (shorts)
  const int sw = l16 & 7;                              // reader swizzle key (= row&7)

  // wave w stages A tile-rows [w*16, w*16+16) : 2 x GLD16 (8 rows each)
  const int r0 = wave * 16;
  const short* Abase = A + (size_t)(m0 + r0 + lane_row) * 4096 + src_col;

  #define STAGE(kt, buf) do {                                                  \
    const short* g_ = Abase + (kt) * 64;                                       \
    GLD16(g_,            &As[(buf) * 8192 + r0 * 64 + lane * 8]);              \
    GLD16(g_ + 8 * 4096, &As[(buf) * 8192 + (r0 + 8) * 64 + lane * 8]);        \
  } while (0)

  float e1n[4], e1c[4];
  STAGE(0, 0);                                   // outstanding: 2
  #pragma unroll
  for (int j = 0; j < 4; j++) e1n[j] = E1t[nrow[j]];          // +4
  STAGE(1, 1);                                   // +2  -> queue [s0:2, e1:4, s1:2]

  int cb = 0, sb = 2;                            // compute buf (kt%3), stage buf ((kt+2)%3)

  #pragma unroll 1
  for (int kt = 0; kt < 64; ++kt) {
    // drain tile kt's stage + e1(kt); keep stage(kt+1)'s 2 loads in flight
    asm volatile("s_waitcnt vmcnt(2)" ::: "memory");
    __builtin_amdgcn_s_barrier();
    asm volatile("" ::: "memory");

    #pragma unroll
    for (int j = 0; j < 4; j++) e1c[j] = e1n[j];
    const int tn = (kt + 1 > 63) ? 63 : kt + 1;            // clamped: uniform vmcnt count
    #pragma unroll
    for (int j = 0; j < 4; j++) e1n[j] = E1t[tn * 8192 + nrow[j]];
    const int ts = (kt + 2 > 63) ? 63 : kt + 2;            // dummy re-stage in tail (dead buf)
    STAGE(ts, sb);

    const short* buf = &As[cb * 8192];

    // all 8 A-fragments for this kt (32 VGPR); compiler schedules lgkm waits
    bf16x8 a[4][2];
    #pragma unroll
    for (int i = 0; i < 4; i++)
      #pragma unroll
      for (int ks = 0; ks < 2; ks++)
        a[i][ks] = *(const bf16x8*)&buf[(wm + i * 16 + l16) * 64 +
                                        (((ks * 4 + quad) ^ sw) * 8)];

    // 4 phases by output column j: build 2 B-frags, then MFMA cluster
    #pragma unroll
    for (int j = 0; j < 4; j++) {
      bf16x8 b[2];
      #pragma unroll
      for (int ks = 0; ks < 2; ks++) {
        const float s = e1c[j];
        bf16x8 bb;
        bb[0] = (__bf16)(s * e2a[j][ks].x);
        bb[1] = (__bf16)(s * e2a[j][ks].y);
        bb[2] = (__bf16)(s * e2a[j][ks].z);
        bb[3] = (__bf16)(s * e2a[j][ks].w);
        bb[4] = (__bf16)(s * e2b[j][ks].x);
        bb[5] = (__bf16)(s * e2b[j][ks].y);
        bb[6] = (__bf16)(s * e2b[j][ks].z);
        bb[7] = (__bf16)(s * e2b[j][ks].w);
        b[ks] = bb;
      }
      __builtin_amdgcn_s_setprio(1);
      #pragma unroll
      for (int ks = 0; ks < 2; ks++)
        #pragma unroll
        for (int i = 0; i < 4; i++)
          acc[i][j] = __builtin_amdgcn_mfma_f32_16x16x32_bf16(a[i][ks], b[ks],
                                                              acc[i][j], 0, 0, 0);
      __builtin_amdgcn_s_setprio(0);
    }

    cb = (cb + 1 == 3) ? 0 : cb + 1;
    sb = (sb + 1 == 3) ? 0 : sb + 1;
  }

  // drain in-flight (dummy) LDS stages before epilogue / endpgm
  asm volatile("s_waitcnt vmcnt(0)" ::: "memory");

  // epilogue: C/D layout col=lane&15, row=quad*4+reg
  #pragma unroll
  for (int i = 0; i < 4; i++) {
    #pragma unroll
    for (int r = 0; r < 4; r++) {
      const int brow = m0 + wm + i * 16 + quad * 4 + r;
      float* crow = C + (size_t)brow * 8192 + n0 + wn + l16;
      #pragma unroll
      for (int j = 0; j < 4; j++) crow[j * 16] = acc[i][j][r];
    }
  }
  #undef STAGE
}

// ---------------- k4: row-normalize d_out (1024 rows of 8192) ----------------
__global__ __launch_bounds__(256) void norm_kernel(float* __restrict__ out) {
  const int b = blockIdx.x;
  const int t = threadIdx.x;
  const int lane = t & 63, wave = t >> 6;
  __shared__ float red[4];

  float4* row = (float4*)(out + (size_t)b * 8192);   // 2048 float4
  float4 v[8];
  float s = 0.0f;
  #pragma unroll
  for (int q = 0; q < 8; q++) {
    v[q] = row[q * 256 + t];
    s += (v[q].x + v[q].y) + (v[q].z + v[q].w);
  }
  float ws = wave_sum(s);
  if (lane == 0) red[wave] = ws;
  __syncthreads();
  float tot = (red[0] + red[1]) + (red[2] + red[3]);
  float inv = 1.0f / tot;
  #pragma unroll
  for (int q = 0; q < 8; q++) {
    v[q].x *= inv; v[q].y *= inv; v[q].z *= inv; v[q].w *= inv;
    row[q * 256 + t] = v[q];
  }
}

// ---------------------------------------------------------------------------
extern "C" void kernel_launch(void* const* d_in, const int* in_sizes, int n_in,
                              void* d_out, int out_size, void* d_ws, size_t ws_size,
                              hipStream_t stream) {
  const float* freq    = (const float*)d_in[0];   // 1024*4096
  const float* kparams = (const float*)d_in[1];   // 8192*4*6
  const float* temp    = (const float*)d_in[2];   // 1
  // d_in[3] = kmer_idcs (recomputed analytically in-kernel)

  float* out = (float*)d_out;                     // 1024*8192 f32

  short* freqb = (short*)d_ws;                    // 1024*4096 bf16 = 8 MiB
  float* E1t   = (float*)(freqb + (size_t)1024 * 4096);  // 64*8192 f32 = 2 MiB
  float* E2    = E1t + (size_t)64 * 8192;                // 8192*64 f32 = 2 MiB

  cast_kernel  <<<4096, 256, 0, stream>>>(freq, freqb);
  tables_kernel<<<2048, 256, 0, stream>>>(kparams, temp, E1t, E2);
  gemm_kernel  <<<dim3(32, 8), 512, 0, stream>>>(freqb, E1t, E2, out);
  norm_kernel  <<<1024, 256, 0, stream>>>(out);
}

// Round 2
// 169.504 us; speedup vs baseline: 1.0594x; 1.0594x over previous
//
#include <hip/hip_runtime.h>

// ---------------------------------------------------------------------------
// ConvFeatureExtractor: profile = rownorm( freq @ softmax(matches/T, axis=1)^T )
//   matches[f,i] = Thi[f, i>>6] + Tlo[f, i&63]  (separable!), F=8192, M=4096,
//   B=1024, K=6.  =>  probs[f,i] = e1[f,i>>6] * e2[f,i&63],  Z = (sum e1)(sum e2).
// R8: faithful port of the verified 256-tile 8-phase template (A-only LDS).
//   BM=256 x BN=128, grid 64x4 = 256 blocks (1/CU), 512 thr (8 waves 4Mx2N,
//   wave tile 64x64). 2 phases/kt, 16 MFMA each, 2 barriers/phase, setprio
//   around MFMA cluster. 3-deep A tile buffers (stage kt+2 during kt, 2
//   GLD16/phase), counted s_waitcnt vmcnt(4) once per kt (never 0 in loop).
//   e1 staged once into LDS (E1s) so no stray VMEM breaks vmcnt counting.
//   LDS = 3*32K (A) + 32K (E1) = 128 KiB.
// ---------------------------------------------------------------------------

typedef __bf16  bf16x8 __attribute__((ext_vector_type(8)));
typedef float   f32x4  __attribute__((ext_vector_type(4)));

#define GLD16(gp, lp)                                                          \
  __builtin_amdgcn_global_load_lds(                                            \
      (const __attribute__((address_space(1))) void*)(gp),                     \
      (__attribute__((address_space(3))) void*)(lp), 16, 0, 0)

__device__ __forceinline__ short f2bf(float x) {
  unsigned u = __float_as_uint(x);
  unsigned r = (u + 0x7fffu + ((u >> 16) & 1u)) >> 16;   // RNE
  return (short)r;
}

__device__ __forceinline__ float wave_max(float v) {
  #pragma unroll
  for (int off = 32; off; off >>= 1) v = fmaxf(v, __shfl_xor(v, off, 64));
  return v;
}
__device__ __forceinline__ float wave_sum(float v) {
  #pragma unroll
  for (int off = 32; off; off >>= 1) v += __shfl_xor(v, off, 64);
  return v;
}

// ---------------- k1: freq f32 -> bf16 ----------------
__global__ __launch_bounds__(256) void cast_kernel(const float* __restrict__ in,
                                                   short* __restrict__ out) {
  int idx = blockIdx.x * 256 + threadIdx.x;      // 4 floats each
  float4 v = ((const float4*)in)[idx];
  short4 o;
  o.x = f2bf(v.x); o.y = f2bf(v.y); o.z = f2bf(v.z); o.w = f2bf(v.w);
  ((short4*)out)[idx] = o;
}

// ---------------- k2: softmax factor tables ----------------
__global__ __launch_bounds__(256) void tables_kernel(const float* __restrict__ kp,
                                                     const float* __restrict__ temp,
                                                     float* __restrict__ E1t,
                                                     float* __restrict__ E2) {
  const int t = threadIdx.x;
  const int lane = t & 63, wave = t >> 6;
  const int f = blockIdx.x * 4 + wave;
  const float* P = kp + f * 24;
  const int d0 = (lane >> 4) & 3, d1 = (lane >> 2) & 3, d2 = lane & 3;
  const float thi = P[d0 * 6 + 0] + P[d1 * 6 + 1] + P[d2 * 6 + 2];
  const float tlo = P[d0 * 6 + 3] + P[d1 * 6 + 4] + P[d2 * 6 + 5];
  const float mxhi = wave_max(thi), mxlo = wave_max(tlo);
  const float invT = 1.0f / temp[0];
  const float e1 = __expf((thi - mxhi) * invT);
  const float e2 = __expf((tlo - mxlo) * invT);
  const float s1 = wave_sum(e1), s2 = wave_sum(e2);
  const float invZ = 1.0f / (s1 * s2);
  E1t[lane * 8192 + f] = e1 * invZ;
  E2[(size_t)f * 64 + lane] = e2;
}

// ---------------- k3: GEMM pooled = A(1024x4096) * B^T, B[f,i]=e1[f,i>>6]e2[f,i&63]
__global__ __launch_bounds__(512, 2) void gemm_kernel(const short* __restrict__ A,
                                                      const float* __restrict__ E1t,
                                                      const float* __restrict__ E2,
                                                      float* __restrict__ C) {
  __shared__ short As[3 * 256 * 64];             // 3 x 32 KiB A tile buffers
  __shared__ float E1s[64 * 128];                // 32 KiB: e1 slice [kt][n-local]

  const int t = threadIdx.x;
  const int lane = t & 63, wave = t >> 6;
  const int quad = lane >> 4, l16 = lane & 15;
  const int m0 = blockIdx.y * 256;               // batch tile
  const int n0 = blockIdx.x * 128;               // filter tile
  const int wm = (wave & 3) * 64;                // wave m-offset (4 waves in M)
  const int wn = (wave >> 2) * 64;               // wave n-offset (2 waves in N)

  f32x4 acc[4][4];
  #pragma unroll
  for (int i = 0; i < 4; i++)
    #pragma unroll
    for (int j = 0; j < 4; j++) acc[i][j] = (f32x4){0.f, 0.f, 0.f, 0.f};

  // preload e2 fragments (f32): lane (l16,quad) of frag (j,ks) covers
  // k-in-slice = (ks*4+quad)*8 + 0..7 for filter row nrow[j]
  int nrow[4];
  #pragma unroll
  for (int j = 0; j < 4; j++) nrow[j] = n0 + wn + j * 16 + l16;
  float4 e2a[4][2], e2b[4][2];
  #pragma unroll
  for (int j = 0; j < 4; j++)
    #pragma unroll
    for (int ks = 0; ks < 2; ks++) {
      const float* p = E2 + (size_t)nrow[j] * 64 + (ks * 4 + quad) * 8;
      e2a[j][ks] = *(const float4*)p;
      e2b[j][ks] = *(const float4*)(p + 4);
    }

  const int lane_row = lane >> 3;                      // 0..7 within 8-row chunk
  const int src_col = ((lane & 7) ^ lane_row) * 8;     // swizzled global col (shorts)
  const int sw = l16 & 7;                              // reader swizzle key (= row&7)

  // wave w stages tile rows [32w, 32w+32) as 4 chunks of 8 rows (1 GLD16 each)
  const short* Abase = A + (size_t)(m0 + 32 * wave + lane_row) * 4096 + src_col;
  #define STG(kt, buf, c)                                                      \
    GLD16(Abase + (size_t)(8 * (c)) * 4096 + (kt) * 64,                        \
          &As[(buf) * 16384 + (32 * wave + 8 * (c)) * 64 + lane * 8])

  // ---- prologue: stage E1 slice (4 loads) + tiles 0,1 (4+4 loads) ----
  {
    const int r2 = 2 * wave;                   // wave's 2-row group within each 16
    const float* esrc = E1t + (size_t)r2 * 8192 + n0 + (lane & 31) * 4
                        + (size_t)(lane >> 5) * 8192;
    #pragma unroll
    for (int q = 0; q < 4; q++)
      GLD16(esrc + (size_t)q * 16 * 8192, &E1s[(q * 16 + r2) * 128]);
  }
  #pragma unroll
  for (int c = 0; c < 4; c++) STG(0, 0, c);
  #pragma unroll
  for (int c = 0; c < 4; c++) STG(1, 1, c);
  asm volatile("s_waitcnt vmcnt(4)" ::: "memory");   // E1 + tile0 landed; tile1 in flight
  __builtin_amdgcn_s_barrier();

  int cb = 0, sb = 2;                          // compute buf (kt%3), stage buf (kt+2)%3

  #pragma unroll 1
  for (int kt = 0; kt < 64; ++kt) {
    const short* buf = &As[cb * 16384];
    const int ts = (kt + 2 > 63) ? 63 : kt + 2;      // tail: dummy re-stage, dead buf

    // ================= phase 0: m-frags 0,1 =================
    bf16x8 a0[2][2];
    #pragma unroll
    for (int i = 0; i < 2; i++)
      #pragma unroll
      for (int ks = 0; ks < 2; ks++)
        a0[i][ks] = *(const bf16x8*)&buf[(wm + i * 16 + l16) * 64 +
                                         (((ks * 4 + quad) ^ sw) * 8)];
    float e1c[4];
    #pragma unroll
    for (int j = 0; j < 4; j++) e1c[j] = E1s[kt * 128 + wn + j * 16 + l16];

    bf16x8 b[2][4];
    #pragma unroll
    for (int j = 0; j < 4; j++)
      #pragma unroll
      for (int ks = 0; ks < 2; ks++) {
        const float s = e1c[j];
        bf16x8 bb;
        bb[0] = (__bf16)(s * e2a[j][ks].x);
        bb[1] = (__bf16)(s * e2a[j][ks].y);
        bb[2] = (__bf16)(s * e2a[j][ks].z);
        bb[3] = (__bf16)(s * e2a[j][ks].w);
        bb[4] = (__bf16)(s * e2b[j][ks].x);
        bb[5] = (__bf16)(s * e2b[j][ks].y);
        bb[6] = (__bf16)(s * e2b[j][ks].z);
        bb[7] = (__bf16)(s * e2b[j][ks].w);
        b[ks][j] = bb;
      }

    STG(ts, sb, 0);
    STG(ts, sb, 1);

    __builtin_amdgcn_s_barrier();
    __builtin_amdgcn_sched_barrier(0);
    __builtin_amdgcn_s_setprio(1);
    #pragma unroll
    for (int j = 0; j < 4; j++)
      #pragma unroll
      for (int i = 0; i < 2; i++)
        #pragma unroll
        for (int ks = 0; ks < 2; ks++)
          acc[i][j] = __builtin_amdgcn_mfma_f32_16x16x32_bf16(a0[i][ks], b[ks][j],
                                                              acc[i][j], 0, 0, 0);
    __builtin_amdgcn_s_setprio(0);
    __builtin_amdgcn_s_barrier();

    // ================= phase 1: m-frags 2,3 =================
    bf16x8 a1[2][2];
    #pragma unroll
    for (int i = 0; i < 2; i++)
      #pragma unroll
      for (int ks = 0; ks < 2; ks++)
        a1[i][ks] = *(const bf16x8*)&buf[(wm + 32 + i * 16 + l16) * 64 +
                                         (((ks * 4 + quad) ^ sw) * 8)];
    STG(ts, sb, 2);
    STG(ts, sb, 3);

    // end-of-kt counted drain: tile kt+1's 4 loads land; tile kt+2's stay in flight
    asm volatile("s_waitcnt vmcnt(4)" ::: "memory");
    __builtin_amdgcn_s_barrier();
    __builtin_amdgcn_sched_barrier(0);
    __builtin_amdgcn_s_setprio(1);
    #pragma unroll
    for (int j = 0; j < 4; j++)
      #pragma unroll
      for (int i = 0; i < 2; i++)
        #pragma unroll
        for (int ks = 0; ks < 2; ks++)
          acc[i + 2][j] = __builtin_amdgcn_mfma_f32_16x16x32_bf16(a1[i][ks], b[ks][j],
                                                                  acc[i + 2][j], 0, 0, 0);
    __builtin_amdgcn_s_setprio(0);
    __builtin_amdgcn_s_barrier();

    cb = (cb + 1 == 3) ? 0 : cb + 1;
    sb = (sb + 1 == 3) ? 0 : sb + 1;
  }

  asm volatile("s_waitcnt vmcnt(0)" ::: "memory");   // drain tail dummy stages

  // epilogue: C/D layout col=lane&15, row=quad*4+reg
  #pragma unroll
  for (int i = 0; i < 4; i++) {
    #pragma unroll
    for (int r = 0; r < 4; r++) {
      const int brow = m0 + wm + i * 16 + quad * 4 + r;
      float* crow = C + (size_t)brow * 8192 + n0 + wn + l16;
      #pragma unroll
      for (int j = 0; j < 4; j++) crow[j * 16] = acc[i][j][r];
    }
  }
  #undef STG
}

// ---------------- k4: row-normalize d_out (1024 rows of 8192) ----------------
__global__ __launch_bounds__(256) void norm_kernel(float* __restrict__ out) {
  const int b = blockIdx.x;
  const int t = threadIdx.x;
  const int lane = t & 63, wave = t >> 6;
  __shared__ float red[4];

  float4* row = (float4*)(out + (size_t)b * 8192);   // 2048 float4
  float4 v[8];
  float s = 0.0f;
  #pragma unroll
  for (int q = 0; q < 8; q++) {
    v[q] = row[q * 256 + t];
    s += (v[q].x + v[q].y) + (v[q].z + v[q].w);
  }
  float ws = wave_sum(s);
  if (lane == 0) red[wave] = ws;
  __syncthreads();
  float tot = (red[0] + red[1]) + (red[2] + red[3]);
  float inv = 1.0f / tot;
  #pragma unroll
  for (int q = 0; q < 8; q++) {
    v[q].x *= inv; v[q].y *= inv; v[q].z *= inv; v[q].w *= inv;
    row[q * 256 + t] = v[q];
  }
}

// ---------------------------------------------------------------------------
extern "C" void kernel_launch(void* const* d_in, const int* in_sizes, int n_in,
                              void* d_out, int out_size, void* d_ws, size_t ws_size,
                              hipStream_t stream) {
  const float* freq    = (const float*)d_in[0];   // 1024*4096
  const float* kparams = (const float*)d_in[1];   // 8192*4*6
  const float* temp    = (const float*)d_in[2];   // 1
  // d_in[3] = kmer_idcs (recomputed analytically in-kernel)

  float* out = (float*)d_out;                     // 1024*8192 f32

  short* freqb = (short*)d_ws;                    // 1024*4096 bf16 = 8 MiB
  float* E1t   = (float*)(freqb + (size_t)1024 * 4096);  // 64*8192 f32 = 2 MiB
  float* E2    = E1t + (size_t)64 * 8192;                // 8192*64 f32 = 2 MiB

  cast_kernel  <<<4096, 256, 0, stream>>>(freq, freqb);
  tables_kernel<<<2048, 256, 0, stream>>>(kparams, temp, E1t, E2);
  gemm_kernel  <<<dim3(64, 4), 512, 0, stream>>>(freqb, E1t, E2, out);
  norm_kernel  <<<1024, 256, 0, stream>>>(out);
}

// Round 3
// 159.323 us; speedup vs baseline: 1.1271x; 1.0639x over previous
//
#include <hip/hip_runtime.h>

// ---------------------------------------------------------------------------
// ConvFeatureExtractor: profile = rownorm( freq @ softmax(matches/T, axis=1)^T )
//   matches[f,i] = Thi[f, i>>6] + Tlo[f, i&63]  (separable!), F=8192, M=4096,
//   B=1024, K=6.  =>  probs[f,i] = e1[f,i>>6] * e2[f,i&63],  Z = (sum e1)(sum e2).
// R9: dataflow fix. R6-R8 all plateaued at ~30-35% MfmaUtil because the
//   per-kt B-build (bf16(e1*e2), ~128 VALU ops) is a serial dependency in
//   front of every MFMA cluster -> VALU and MFMA can't overlap.
//   Re-associate:  pooled = sum_kt e1[f,kt] * (A_kt x e2)  -- MFMA runs on
//   CONSTANT bf16 e2 fragments (built once), per-kt partial P (C=0 chain),
//   then acc += e1*P (one f32 FMA per acc value, e1 per-lane scalar since
//   C/D col = lane&15 = f). Loop VALU halves and flips to MFMA->VALU, so the
//   pipes overlap. Geometry: TM=64 x TN=256, 4 waves (1Mx4N, wave 64x64),
//   grid 32x16 = 512 blocks = 2/CU. Ping-pong 8KB A tiles, stage(kt+1) +
//   e1(kt+1) issued a full iter ahead under counted vmcnt(6). LDS = 16 KiB.
// ---------------------------------------------------------------------------

typedef __bf16  bf16x8 __attribute__((ext_vector_type(8)));
typedef float   f32x4  __attribute__((ext_vector_type(4)));

#define GLD16(gp, lp)                                                          \
  __builtin_amdgcn_global_load_lds(                                            \
      (const __attribute__((address_space(1))) void*)(gp),                     \
      (__attribute__((address_space(3))) void*)(lp), 16, 0, 0)

__device__ __forceinline__ short f2bf(float x) {
  unsigned u = __float_as_uint(x);
  unsigned r = (u + 0x7fffu + ((u >> 16) & 1u)) >> 16;   // RNE
  return (short)r;
}

__device__ __forceinline__ float wave_max(float v) {
  #pragma unroll
  for (int off = 32; off; off >>= 1) v = fmaxf(v, __shfl_xor(v, off, 64));
  return v;
}
__device__ __forceinline__ float wave_sum(float v) {
  #pragma unroll
  for (int off = 32; off; off >>= 1) v += __shfl_xor(v, off, 64);
  return v;
}

// ---------------- k1: freq f32 -> bf16 ----------------
__global__ __launch_bounds__(256) void cast_kernel(const float* __restrict__ in,
                                                   short* __restrict__ out) {
  int idx = blockIdx.x * 256 + threadIdx.x;      // 4 floats each
  float4 v = ((const float4*)in)[idx];
  short4 o;
  o.x = f2bf(v.x); o.y = f2bf(v.y); o.z = f2bf(v.z); o.w = f2bf(v.w);
  ((short4*)out)[idx] = o;
}

// ---------------- k2: softmax factor tables ----------------
__global__ __launch_bounds__(256) void tables_kernel(const float* __restrict__ kp,
                                                     const float* __restrict__ temp,
                                                     float* __restrict__ E1t,
                                                     float* __restrict__ E2) {
  const int t = threadIdx.x;
  const int lane = t & 63, wave = t >> 6;
  const int f = blockIdx.x * 4 + wave;
  const float* P = kp + f * 24;
  const int d0 = (lane >> 4) & 3, d1 = (lane >> 2) & 3, d2 = lane & 3;
  const float thi = P[d0 * 6 + 0] + P[d1 * 6 + 1] + P[d2 * 6 + 2];
  const float tlo = P[d0 * 6 + 3] + P[d1 * 6 + 4] + P[d2 * 6 + 5];
  const float mxhi = wave_max(thi), mxlo = wave_max(tlo);
  const float invT = 1.0f / temp[0];
  const float e1 = __expf((thi - mxhi) * invT);
  const float e2 = __expf((tlo - mxlo) * invT);
  const float s1 = wave_sum(e1), s2 = wave_sum(e2);
  const float invZ = 1.0f / (s1 * s2);
  E1t[lane * 8192 + f] = e1 * invZ;
  E2[(size_t)f * 64 + lane] = e2;
}

// ---------------- k3: GEMM pooled = A(1024x4096) * B^T, B[f,i]=e1[f,i>>6]e2[f,i&63]
// TM=64, TN=256, BK=64; grid 32x16 = 512 blocks (2/CU), 4 waves 1Mx4N.
// Wave tile 64x64 = 4x4 frags. A-only LDS (XOR-swizzled src), ping-pong 8KB.
// Per kt: issue stage(kt+1)+e1(kt+1) [6 VMEM]; vmcnt(6); barrier;
//   P = mfma(a0,e2f0, mfma-chain 0-init); acc += e1c * P; barrier.
__global__ __launch_bounds__(256, 2) void gemm_kernel(const short* __restrict__ A,
                                                      const float* __restrict__ E1t,
                                                      const float* __restrict__ E2,
                                                      float* __restrict__ C) {
  __shared__ short As[2][64 * 64];               // 2 x 8 KiB ping-pong

  const int t = threadIdx.x;
  const int lane = t & 63, wave = t >> 6;
  const int quad = lane >> 4, l16 = lane & 15;
  const int m0 = blockIdx.y * 64;                // batch tile
  const int n0 = blockIdx.x * 256;               // filter tile
  const int wn = wave * 64;                      // wave's n-offset

  f32x4 acc[4][4];
  #pragma unroll
  for (int i = 0; i < 4; i++)
    #pragma unroll
    for (int j = 0; j < 4; j++) acc[i][j] = (f32x4){0.f, 0.f, 0.f, 0.f};

  // prebuild CONSTANT bf16 e2 fragments (e1-independent): lane (l16,quad) of
  // frag (ks,j) covers k = (ks*4+quad)*8 + 0..7 for filter row nrow[j]
  int nrow[4];
  #pragma unroll
  for (int j = 0; j < 4; j++) nrow[j] = n0 + wn + j * 16 + l16;
  bf16x8 e2f[2][4];
  #pragma unroll
  for (int j = 0; j < 4; j++)
    #pragma unroll
    for (int ks = 0; ks < 2; ks++) {
      const float* p = E2 + (size_t)nrow[j] * 64 + (ks * 4 + quad) * 8;
      float4 lo = *(const float4*)p, hi = *(const float4*)(p + 4);
      bf16x8 bb;
      bb[0] = (__bf16)lo.x; bb[1] = (__bf16)lo.y;
      bb[2] = (__bf16)lo.z; bb[3] = (__bf16)lo.w;
      bb[4] = (__bf16)hi.x; bb[5] = (__bf16)hi.y;
      bb[6] = (__bf16)hi.z; bb[7] = (__bf16)hi.w;
      e2f[ks][j] = bb;
    }

  const int lane_row = lane >> 3;                      // 0..7 within 8-row chunk
  const int src_col = ((lane & 7) ^ lane_row) * 8;     // swizzled global col (shorts)
  const int sw = l16 & 7;                              // reader swizzle key (= row&7)
  const int chunk = wave * 2;                          // wave stages chunks 2w, 2w+1
  const short* Abase = A + (size_t)(m0 + lane_row) * 4096 + src_col;

  #define STG(kt, buf) do {                                                    \
    GLD16(Abase + (size_t)((chunk + 0) * 8) * 4096 + (kt) * 64,                \
          &As[buf][(chunk + 0) * 512 + lane * 8]);                             \
    GLD16(Abase + (size_t)((chunk + 1) * 8) * 4096 + (kt) * 64,                \
          &As[buf][(chunk + 1) * 512 + lane * 8]);                             \
  } while (0)

  // prologue: tile 0 + e1(0)  -> 6 VMEM outstanding
  STG(0, 0);
  float e1n[4], e1c[4];
  #pragma unroll
  for (int j = 0; j < 4; j++) e1n[j] = E1t[nrow[j]];

  const f32x4 Z4 = (f32x4){0.f, 0.f, 0.f, 0.f};

  #pragma unroll 1
  for (int kt = 0; kt < 64; ++kt) {
    const int cb = kt & 1;
    const int tn = (kt + 1 > 63) ? 63 : kt + 1;        // tail: dummy restage/reload

    STG(tn, cb ^ 1);                                   // +2 VMEM (full-iter flight)
    #pragma unroll
    for (int j = 0; j < 4; j++) e1c[j] = e1n[j];
    #pragma unroll
    for (int j = 0; j < 4; j++) e1n[j] = E1t[tn * 8192 + nrow[j]];  // +4 VMEM

    // wait tile kt's 6 VMEM (issued last iter); kt+1's 6 stay in flight
    asm volatile("s_waitcnt vmcnt(6)" ::: "memory");
    __builtin_amdgcn_s_barrier();

    bf16x8 a[4][2];
    #pragma unroll
    for (int i = 0; i < 4; i++)
      #pragma unroll
      for (int ks = 0; ks < 2; ks++)
        a[i][ks] = *(const bf16x8*)&As[cb][(i * 16 + l16) * 64 +
                                          (((ks * 4 + quad) ^ sw) * 8)];

    __builtin_amdgcn_s_setprio(1);
    #pragma unroll
    for (int j = 0; j < 4; j++) {
      const f32x4 s4 = (f32x4){e1c[j], e1c[j], e1c[j], e1c[j]};
      #pragma unroll
      for (int i = 0; i < 4; i++) {
        f32x4 P = __builtin_amdgcn_mfma_f32_16x16x32_bf16(a[i][0], e2f[0][j], Z4, 0, 0, 0);
        P = __builtin_amdgcn_mfma_f32_16x16x32_bf16(a[i][1], e2f[1][j], P, 0, 0, 0);
        acc[i][j] += s4 * P;                           // f32 FMA; e1 folded here
      }
    }
    __builtin_amdgcn_s_setprio(0);
    __builtin_amdgcn_s_barrier();                      // readers done before restage
  }

  asm volatile("s_waitcnt vmcnt(0)" ::: "memory");     // drain tail dummies

  // epilogue: C/D layout col=lane&15, row=quad*4+reg
  #pragma unroll
  for (int i = 0; i < 4; i++) {
    #pragma unroll
    for (int r = 0; r < 4; r++) {
      const int brow = m0 + i * 16 + quad * 4 + r;
      float* crow = C + (size_t)brow * 8192 + n0 + wn + l16;
      #pragma unroll
      for (int j = 0; j < 4; j++) crow[j * 16] = acc[i][j][r];
    }
  }
  #undef STG
}

// ---------------- k4: row-normalize d_out (1024 rows of 8192) ----------------
__global__ __launch_bounds__(256) void norm_kernel(float* __restrict__ out) {
  const int b = blockIdx.x;
  const int t = threadIdx.x;
  const int lane = t & 63, wave = t >> 6;
  __shared__ float red[4];

  float4* row = (float4*)(out + (size_t)b * 8192);   // 2048 float4
  float4 v[8];
  float s = 0.0f;
  #pragma unroll
  for (int q = 0; q < 8; q++) {
    v[q] = row[q * 256 + t];
    s += (v[q].x + v[q].y) + (v[q].z + v[q].w);
  }
  float ws = wave_sum(s);
  if (lane == 0) red[wave] = ws;
  __syncthreads();
  float tot = (red[0] + red[1]) + (red[2] + red[3]);
  float inv = 1.0f / tot;
  #pragma unroll
  for (int q = 0; q < 8; q++) {
    v[q].x *= inv; v[q].y *= inv; v[q].z *= inv; v[q].w *= inv;
    row[q * 256 + t] = v[q];
  }
}

// ---------------------------------------------------------------------------
extern "C" void kernel_launch(void* const* d_in, const int* in_sizes, int n_in,
                              void* d_out, int out_size, void* d_ws, size_t ws_size,
                              hipStream_t stream) {
  const float* freq    = (const float*)d_in[0];   // 1024*4096
  const float* kparams = (const float*)d_in[1];   // 8192*4*6
  const float* temp    = (const float*)d_in[2];   // 1
  // d_in[3] = kmer_idcs (recomputed analytically in-kernel)

  float* out = (float*)d_out;                     // 1024*8192 f32

  short* freqb = (short*)d_ws;                    // 1024*4096 bf16 = 8 MiB
  float* E1t   = (float*)(freqb + (size_t)1024 * 4096);  // 64*8192 f32 = 2 MiB
  float* E2    = E1t + (size_t)64 * 8192;                // 8192*64 f32 = 2 MiB

  cast_kernel  <<<4096, 256, 0, stream>>>(freq, freqb);
  tables_kernel<<<2048, 256, 0, stream>>>(kparams, temp, E1t, E2);
  gemm_kernel  <<<dim3(32, 16), 256, 0, stream>>>(freqb, E1t, E2, out);
  norm_kernel  <<<1024, 256, 0, stream>>>(out);
}

// Round 4
// 157.895 us; speedup vs baseline: 1.1373x; 1.0090x over previous
//
#include <hip/hip_runtime.h>

// ---------------------------------------------------------------------------
// ConvFeatureExtractor: profile = rownorm( freq @ softmax(matches/T, axis=1)^T )
//   matches[f,i] = Thi[f, i>>6] + Tlo[f, i&63]  (separable!), F=8192, M=4096,
//   B=1024, K=6.  =>  probs[f,i] = e1[f,i>>6] * e2[f,i&63],  Z = (sum e1)(sum e2).
// R10: stall-hiding fix on top of R9's re-associated dataflow
//   ( pooled = sum_kt e1[f,kt] * (A_kt x e2),  MFMA on constant e2 frags ).
//   R9 counters: MfmaUtil 37%, VALU 25%, occupancy 19% (2 streams/SIMD),
//   ~1100 cyc/kt naked sync stall. Changes:
//   1) TN 256->128: grid 64x16=1024 blocks = 4 blocks/CU = 4 independent
//      barrier-domains per SIMD (16 waves/CU) to hide each other's stalls.
//   2) 3-deep A buffers (stage kt+2 during kt) -> ONE barrier per kt
//      (restage target last read at kt-1; top barrier orders it).
//      Counted vmcnt(4) covers the LDS-destined stage only.
//   3) XCD-aware dispatch remap: XCD k owns 2 consecutive m-strips, so A
//      re-reads (doubled by TN=128) are L2 hits, not fabric traffic.
// ---------------------------------------------------------------------------

typedef __bf16  bf16x8 __attribute__((ext_vector_type(8)));
typedef float   f32x4  __attribute__((ext_vector_type(4)));

#define GLD16(gp, lp)                                                          \
  __builtin_amdgcn_global_load_lds(                                            \
      (const __attribute__((address_space(1))) void*)(gp),                     \
      (__attribute__((address_space(3))) void*)(lp), 16, 0, 0)

__device__ __forceinline__ short f2bf(float x) {
  unsigned u = __float_as_uint(x);
  unsigned r = (u + 0x7fffu + ((u >> 16) & 1u)) >> 16;   // RNE
  return (short)r;
}

__device__ __forceinline__ float wave_max(float v) {
  #pragma unroll
  for (int off = 32; off; off >>= 1) v = fmaxf(v, __shfl_xor(v, off, 64));
  return v;
}
__device__ __forceinline__ float wave_sum(float v) {
  #pragma unroll
  for (int off = 32; off; off >>= 1) v += __shfl_xor(v, off, 64);
  return v;
}

// ---------------- k1: freq f32 -> bf16 ----------------
__global__ __launch_bounds__(256) void cast_kernel(const float* __restrict__ in,
                                                   short* __restrict__ out) {
  int idx = blockIdx.x * 256 + threadIdx.x;      // 4 floats each
  float4 v = ((const float4*)in)[idx];
  short4 o;
  o.x = f2bf(v.x); o.y = f2bf(v.y); o.z = f2bf(v.z); o.w = f2bf(v.w);
  ((short4*)out)[idx] = o;
}

// ---------------- k2: softmax factor tables ----------------
__global__ __launch_bounds__(256) void tables_kernel(const float* __restrict__ kp,
                                                     const float* __restrict__ temp,
                                                     float* __restrict__ E1t,
                                                     float* __restrict__ E2) {
  const int t = threadIdx.x;
  const int lane = t & 63, wave = t >> 6;
  const int f = blockIdx.x * 4 + wave;
  const float* P = kp + f * 24;
  const int d0 = (lane >> 4) & 3, d1 = (lane >> 2) & 3, d2 = lane & 3;
  const float thi = P[d0 * 6 + 0] + P[d1 * 6 + 1] + P[d2 * 6 + 2];
  const float tlo = P[d0 * 6 + 3] + P[d1 * 6 + 4] + P[d2 * 6 + 5];
  const float mxhi = wave_max(thi), mxlo = wave_max(tlo);
  const float invT = 1.0f / temp[0];
  const float e1 = __expf((thi - mxhi) * invT);
  const float e2 = __expf((tlo - mxlo) * invT);
  const float s1 = wave_sum(e1), s2 = wave_sum(e2);
  const float invZ = 1.0f / (s1 * s2);
  E1t[lane * 8192 + f] = e1 * invZ;
  E2[(size_t)f * 64 + lane] = e2;
}

// ---------------- k3: GEMM pooled = A(1024x4096) * B^T, B[f,i]=e1[f,i>>6]e2[f,i&63]
// TM=64, TN=128, BK=64; grid 1024 blocks (4/CU), 4 waves 1Mx4N (wave 64x32).
// XCD remap: dispatch d -> XCD d%8 owns m-strips {2k,2k+1} (A slice 1MB in L2).
// 3-deep 8KB A buffers, 1 barrier/kt, counted vmcnt(4).
__global__ __launch_bounds__(256, 4) void gemm_kernel(const short* __restrict__ A,
                                                      const float* __restrict__ E1t,
                                                      const float* __restrict__ E2,
                                                      float* __restrict__ C) {
  __shared__ short As[3][64 * 64];               // 3 x 8 KiB rotating buffers

  const int t = threadIdx.x;
  const int lane = t & 63, wave = t >> 6;
  const int quad = lane >> 4, l16 = lane & 15;

  // XCD-aware remap: d = dispatch order (x fastest); XCD k = d%8 gets the
  // contiguous L-range [k*128, (k+1)*128) = m-strips {2k, 2k+1}.
  const int d  = blockIdx.y * 64 + blockIdx.x;
  const int L  = (d & 7) * 128 + (d >> 3);
  const int m0 = (L >> 6) * 64;                  // batch tile (16 strips)
  const int n0 = (L & 63) * 128;                 // filter tile (64 strips)
  const int wn = wave * 32;                      // wave's n-offset

  f32x4 acc[4][2];
  #pragma unroll
  for (int i = 0; i < 4; i++)
    #pragma unroll
    for (int j = 0; j < 2; j++) acc[i][j] = (f32x4){0.f, 0.f, 0.f, 0.f};

  // constant bf16 e2 fragments (e1-independent): lane (l16,quad) of frag
  // (ks,j) covers k = (ks*4+quad)*8 + 0..7 for filter row nrow[j]
  int nrow[2];
  #pragma unroll
  for (int j = 0; j < 2; j++) nrow[j] = n0 + wn + j * 16 + l16;
  bf16x8 e2f[2][2];
  #pragma unroll
  for (int j = 0; j < 2; j++)
    #pragma unroll
    for (int ks = 0; ks < 2; ks++) {
      const float* p = E2 + (size_t)nrow[j] * 64 + (ks * 4 + quad) * 8;
      float4 lo = *(const float4*)p, hi = *(const float4*)(p + 4);
      bf16x8 bb;
      bb[0] = (__bf16)lo.x; bb[1] = (__bf16)lo.y;
      bb[2] = (__bf16)lo.z; bb[3] = (__bf16)lo.w;
      bb[4] = (__bf16)hi.x; bb[5] = (__bf16)hi.y;
      bb[6] = (__bf16)hi.z; bb[7] = (__bf16)hi.w;
      e2f[ks][j] = bb;
    }

  const int lane_row = lane >> 3;                      // 0..7 within 8-row chunk
  const int src_col = ((lane & 7) ^ lane_row) * 8;     // swizzled global col (shorts)
  const int sw = l16 & 7;                              // reader swizzle key (= row&7)
  const int chunk = wave * 2;                          // wave stages chunks 2w, 2w+1
  const short* Abase = A + (size_t)(m0 + lane_row) * 4096 + src_col;

  #define STG(kt, buf) do {                                                    \
    GLD16(Abase + (size_t)((chunk + 0) * 8) * 4096 + (kt) * 64,                \
          &As[buf][(chunk + 0) * 512 + lane * 8]);                             \
    GLD16(Abase + (size_t)((chunk + 1) * 8) * 4096 + (kt) * 64,                \
          &As[buf][(chunk + 1) * 512 + lane * 8]);                             \
  } while (0)

  // prologue: S(0), e1(0), S(1)  -> 6 VMEM outstanding
  STG(0, 0);
  float e1n[2], e1c[2];
  #pragma unroll
  for (int j = 0; j < 2; j++) e1n[j] = E1t[nrow[j]];
  STG(1, 1);

  const f32x4 Z4 = (f32x4){0.f, 0.f, 0.f, 0.f};

  #pragma unroll 1
  for (int kt = 0; kt < 64; ++kt) {
    const int cb = kt % 3;
    const int sb = (kt + 2) % 3;
    const int tn = (kt + 1 > 63) ? 63 : kt + 1;        // tail: dummy reload
    const int ts = (kt + 2 > 63) ? 63 : kt + 2;        // tail: dummy restage

    // S(kt) is the oldest <=6 outstanding VMEM; drain to 4 -> S(kt) landed.
    // (e1 reads are VGPR-dest: compiler inserts its own vmcnt waits.)
    asm volatile("s_waitcnt vmcnt(4)" ::: "memory");
    __builtin_amdgcn_s_barrier();                      // publish tile kt

    bf16x8 a[4][2];
    #pragma unroll
    for (int i = 0; i < 4; i++)
      #pragma unroll
      for (int ks = 0; ks < 2; ks++)
        a[i][ks] = *(const bf16x8*)&As[cb][(i * 16 + l16) * 64 +
                                          (((ks * 4 + quad) ^ sw) * 8)];

    #pragma unroll
    for (int j = 0; j < 2; j++) e1c[j] = e1n[j];
    #pragma unroll
    for (int j = 0; j < 2; j++) e1n[j] = E1t[tn * 8192 + nrow[j]];  // +2 VMEM
    STG(ts, sb);                                                    // +2 VMEM

    __builtin_amdgcn_s_setprio(1);
    #pragma unroll
    for (int j = 0; j < 2; j++) {
      const f32x4 s4 = (f32x4){e1c[j], e1c[j], e1c[j], e1c[j]};
      #pragma unroll
      for (int i = 0; i < 4; i++) {
        f32x4 P = __builtin_amdgcn_mfma_f32_16x16x32_bf16(a[i][0], e2f[0][j], Z4, 0, 0, 0);
        P = __builtin_amdgcn_mfma_f32_16x16x32_bf16(a[i][1], e2f[1][j], P, 0, 0, 0);
        acc[i][j] += s4 * P;                           // f32 FMA; e1 folded here
      }
    }
    __builtin_amdgcn_s_setprio(0);
    // no bottom barrier: restage target (kt+2)%3 was last read at kt-1, and
    // every wave's kt-1 reads drained before it passed THIS kt's barrier.
  }

  asm volatile("s_waitcnt vmcnt(0)" ::: "memory");     // drain tail dummies

  // epilogue: C/D layout col=lane&15, row=quad*4+reg
  #pragma unroll
  for (int i = 0; i < 4; i++) {
    #pragma unroll
    for (int r = 0; r < 4; r++) {
      const int brow = m0 + i * 16 + quad * 4 + r;
      float* crow = C + (size_t)brow * 8192 + n0 + wn + l16;
      #pragma unroll
      for (int j = 0; j < 2; j++) crow[j * 16] = acc[i][j][r];
    }
  }
  #undef STG
}

// ---------------- k4: row-normalize d_out (1024 rows of 8192) ----------------
__global__ __launch_bounds__(256) void norm_kernel(float* __restrict__ out) {
  const int b = blockIdx.x;
  const int t = threadIdx.x;
  const int lane = t & 63, wave = t >> 6;
  __shared__ float red[4];

  float4* row = (float4*)(out + (size_t)b * 8192);   // 2048 float4
  float4 v[8];
  float s = 0.0f;
  #pragma unroll
  for (int q = 0; q < 8; q++) {
    v[q] = row[q * 256 + t];
    s += (v[q].x + v[q].y) + (v[q].z + v[q].w);
  }
  float ws = wave_sum(s);
  if (lane == 0) red[wave] = ws;
  __syncthreads();
  float tot = (red[0] + red[1]) + (red[2] + red[3]);
  float inv = 1.0f / tot;
  #pragma unroll
  for (int q = 0; q < 8; q++) {
    v[q].x *= inv; v[q].y *= inv; v[q].z *= inv; v[q].w *= inv;
    row[q * 256 + t] = v[q];
  }
}

// ---------------------------------------------------------------------------
extern "C" void kernel_launch(void* const* d_in, const int* in_sizes, int n_in,
                              void* d_out, int out_size, void* d_ws, size_t ws_size,
                              hipStream_t stream) {
  const float* freq    = (const float*)d_in[0];   // 1024*4096
  const float* kparams = (const float*)d_in[1];   // 8192*4*6
  const float* temp    = (const float*)d_in[2];   // 1
  // d_in[3] = kmer_idcs (recomputed analytically in-kernel)

  float* out = (float*)d_out;                     // 1024*8192 f32

  short* freqb = (short*)d_ws;                    // 1024*4096 bf16 = 8 MiB
  float* E1t   = (float*)(freqb + (size_t)1024 * 4096);  // 64*8192 f32 = 2 MiB
  float* E2    = E1t + (size_t)64 * 8192;                // 8192*64 f32 = 2 MiB

  cast_kernel  <<<4096, 256, 0, stream>>>(freq, freqb);
  tables_kernel<<<2048, 256, 0, stream>>>(kparams, temp, E1t, E2);
  gemm_kernel  <<<dim3(64, 16), 256, 0, stream>>>(freqb, E1t, E2, out);
  norm_kernel  <<<1024, 256, 0, stream>>>(out);
}